// Round 3
// baseline (7051.243 us; speedup 1.0000x reference)
//
#include <hip/hip_runtime.h>
#include <hip/hip_fp16.h>
#include <math.h>

// Problem constants
#define NN 4096
#define NP1 4097
#define DD 128
#define ITERS 100
#define NBLK 256      // persistent blocks = 16x16 tile grid, 1 per CU
#define TPB 512
#define LDA 264       // LDS tile row stride in halfs (256 + 8 pad)
#define FLAG_STRIDE 16  // dwords per flag slot (64B line each)

#define KSCALE 0.0625f
#define MU_C (1.0f/8192.0f)   // exp(norm)
#define MU_B 0.5f             // ns/(ms+ns)
#define INV_SQRT_D 0.08838834764831845f
#define OUT_SCALE 512.0f      // 8192 * KSCALE

#define SMEM_BYTES (135168 + (256 + 256 + 2048 + 8) * 4)

// 16-block group barrier: relaxed polls, single release/acquire fences.
// flags: 16 slots, each FLAG_STRIDE dwords apart (own cache line).
// 0xAA-poisoned slots read negative, so gen >= 1 needs no init.
__device__ __forceinline__ void group_bar(int* flags, int self, int gen) {
  __syncthreads();  // drains vmcnt: all block's stores reached L2
  __builtin_amdgcn_fence(__ATOMIC_RELEASE, "agent");  // wb L2 once
  if (threadIdx.x == 0)
    __hip_atomic_store(flags + self * FLAG_STRIDE, gen, __ATOMIC_RELAXED,
                       __HIP_MEMORY_SCOPE_AGENT);
  if (threadIdx.x < 16) {
    while (__hip_atomic_load(flags + threadIdx.x * FLAG_STRIDE, __ATOMIC_RELAXED,
                             __HIP_MEMORY_SCOPE_AGENT) < gen)
      __builtin_amdgcn_s_sleep(1);
  }
  __syncthreads();
  __builtin_amdgcn_fence(__ATOMIC_ACQUIRE, "agent");  // inv caches once
}

// ---------------- GEMM: c[i][j] = sum_d A[d][i]*B[d][j] / sqrt(128) -------
__global__ __launch_bounds__(256) void gemm_kernel(
    const float* __restrict__ A, const float* __restrict__ B,
    float* __restrict__ C) {
  __shared__ float As[16][64];
  __shared__ float Bs[16][64];
  const int tid = threadIdx.x;
  const int tx = tid & 15, ty = tid >> 4;
  const int i0 = blockIdx.y * 64, j0 = blockIdx.x * 64;
  float acc[4][4] = {};
  for (int k0 = 0; k0 < DD; k0 += 16) {
#pragma unroll
    for (int l = 0; l < 4; ++l) {
      int idx = tid + l * 256;
      int r = idx >> 6, cc = idx & 63;
      As[r][cc] = A[(k0 + r) * NN + i0 + cc];
      Bs[r][cc] = B[(k0 + r) * NN + j0 + cc];
    }
    __syncthreads();
#pragma unroll
    for (int kk = 0; kk < 16; ++kk) {
      float a[4], b[4];
#pragma unroll
      for (int r = 0; r < 4; ++r) a[r] = As[kk][ty * 4 + r];
#pragma unroll
      for (int s = 0; s < 4; ++s) b[s] = Bs[kk][tx * 4 + s];
#pragma unroll
      for (int r = 0; r < 4; ++r)
#pragma unroll
        for (int s = 0; s < 4; ++s) acc[r][s] += a[r] * b[s];
    }
    __syncthreads();
  }
  for (int r = 0; r < 4; ++r)
    for (int s = 0; s < 4; ++s)
      C[(long)(i0 + ty * 4 + r) * NN + j0 + tx * 4 + s] = acc[r][s] * INV_SQRT_D;
}

// -------- persistent Sinkhorn: 100 iterations, K tiles resident in LDS ----
// Block (rb,cb) owns tile rows [rb*256,..), cols [cb*256,..).
// Per iteration: phase A (u-update) syncs only row group rb (16 blocks);
// phase B (v-update) syncs only column group cb. Bin-scalar partials ride
// along with the partial arrays; transitivity of alternating syncs makes
// them globally visible one phase later, matching the recurrences.
__global__ __launch_bounds__(TPB, 1) void sinkhorn_persistent(
    const float* __restrict__ C, const float* __restrict__ alpha_p,
    float* __restrict__ pu, float* __restrict__ pv,
    float* __restrict__ SvArr, float* __restrict__ SuArr,
    int* __restrict__ rowflag, int* __restrict__ colflag,
    float* __restrict__ u_out, float* __restrict__ v_out) {
  extern __shared__ char smem[];
  __half* tile = (__half*)smem;                  // 256 x 264 halfs
  float* v_sh = (float*)(smem + 135168);         // 256
  float* u_sh = v_sh + 256;                      // 256
  float* scratch = u_sh + 256;                   // 2048
  float* red_sh = scratch + 2048;                // 8

  const int tid = threadIdx.x;
  const int bid = blockIdx.x;
  const int rb = bid >> 4, cb = bid & 15;
  const int r0 = rb * 256, c0 = cb * 256;
  const float b = __expf(alpha_p[0]) * KSCALE;

  // ---- load tile: exp(c)*KSCALE -> fp16 LDS ----
  {
    const int l = tid & 63;   // cols 4l..4l+3
    const int rr = tid >> 6;  // 8 rows per sweep
    for (int base = 0; base < 256; base += 8) {
      const int row = base + rr;
      const float4 x =
          *(const float4*)(C + (size_t)(r0 + row) * NN + c0 + l * 4);
      __half2 p0, p1;
      p0.x = __float2half(__expf(x.x) * KSCALE);
      p0.y = __float2half(__expf(x.y) * KSCALE);
      p1.x = __float2half(__expf(x.z) * KSCALE);
      p1.y = __float2half(__expf(x.w) * KSCALE);
      union { __half2 h[2]; float2 f; } uu;
      uu.h[0] = p0; uu.h[1] = p1;
      *(float2*)(tile + row * LDA + l * 4) = uu.f;
    }
  }

  float ubin = 1.0f, vbin = 1.0f;  // bin recurrences (v^0 = 1, vbin^0 = 1)
  float Sv_loc = 256.0f;           // local sum of v^0 over this col group
  int gen = 0;

  for (int t = 1; t <= ITERS; ++t) {
    const int par = (t - 1) & 1;
    if (t == 1) {
      if (tid < 256) v_sh[tid] = 1.0f;
    }
    __syncthreads();  // v_sh (v^{t-1}) visible to all

    // ---- phase A: row-partials of K v^{t-1} ----
    {
      const int l = tid & 63, wv = tid >> 6;
      const int g = l >> 3, cs = l & 7;
      float vseg[32];
      {
        const float4* vp = (const float4*)(v_sh + cs * 32);
#pragma unroll
        for (int k = 0; k < 8; ++k) {
          float4 q = vp[k];
          vseg[4 * k] = q.x; vseg[4 * k + 1] = q.y;
          vseg[4 * k + 2] = q.z; vseg[4 * k + 3] = q.w;
        }
      }
      float* pu_w = pu + (size_t)(par * 16 + cb) * NN + r0;
#pragma unroll
      for (int ii = 0; ii < 4; ++ii) {
        const int row = wv * 32 + ii * 8 + g;
        const float4* kp4 = (const float4*)(tile + row * LDA + cs * 32);
        float acc = 0.f;
#pragma unroll
        for (int q = 0; q < 4; ++q) {
          float4 kraw = kp4[q];
          const __half2* h = (const __half2*)&kraw;
#pragma unroll
          for (int m = 0; m < 4; ++m) {
            float2 kf = __half22float2(h[m]);
            acc += kf.x * vseg[q * 8 + 2 * m] + kf.y * vseg[q * 8 + 2 * m + 1];
          }
        }
        acc += __shfl_xor(acc, 1);
        acc += __shfl_xor(acc, 2);
        acc += __shfl_xor(acc, 4);
        if (cs == 0) pu_w[row] = acc;
      }
    }
    if (tid == 0) SvArr[(par * 16 + rb) * 16 + cb] = Sv_loc;  // Sv_c^{t-1}
    ++gen;
    group_bar(rowflag + rb * 16 * FLAG_STRIDE, cb, gen);

    // ---- assemble u^t (rows r0..r0+255); ubin^t ----
    if (tid < 256) {
      const float* bp = pu + (size_t)par * 16 * NN + r0 + tid;
      float s = 0.f;
#pragma unroll
      for (int k = 0; k < 16; ++k) s += bp[(size_t)k * NN];
      const float* sp = SvArr + par * 256 + rb * 16;
      float svt = 0.f;
#pragma unroll
      for (int k = 0; k < 16; ++k) svt += sp[k];
      ubin = MU_B / (b * (svt + vbin));  // uses global Sv^{t-1} + vbin^{t-1}
      const float ui = MU_C / (s + b * vbin);
      u_sh[tid] = ui;
      float sred = ui;
#pragma unroll
      for (int off = 1; off < 64; off <<= 1) sred += __shfl_xor(sred, off);
      if ((tid & 63) == 0) red_sh[tid >> 6] = sred;
    }
    __syncthreads();
    const float Su_loc = red_sh[0] + red_sh[1] + red_sh[2] + red_sh[3];

    // ---- phase B: col-partials of K^T u^t ----
    {
      const int l = tid & 63, wv = tid >> 6;
      float fa0 = 0.f, fa1 = 0.f, fa2 = 0.f, fa3 = 0.f;
#pragma unroll 8
      for (int r = 0; r < 32; ++r) {
        const int row = wv * 32 + r;
        const float ur = u_sh[row];
        float2 kraw = *(const float2*)(tile + row * LDA + l * 4);
        const __half2* h = (const __half2*)&kraw;
        float2 k0 = __half22float2(h[0]), k1 = __half22float2(h[1]);
        fa0 += k0.x * ur; fa1 += k0.y * ur;
        fa2 += k1.x * ur; fa3 += k1.y * ur;
      }
      float4 fv; fv.x = fa0; fv.y = fa1; fv.z = fa2; fv.w = fa3;
      *(float4*)(scratch + (wv * 64 + l) * 4) = fv;
    }
    __syncthreads();
    if (tid < 256) {
      float s = 0.f;
#pragma unroll
      for (int k = 0; k < 8; ++k) s += scratch[k * 256 + tid];
      pv[(size_t)(par * 16 + rb) * NN + c0 + tid] = s;
    }
    if (tid == 0) SuArr[(par * 16 + cb) * 16 + rb] = Su_loc;  // Su_r^t
    ++gen;
    group_bar(colflag + cb * 16 * FLAG_STRIDE, rb, gen);

    // ---- assemble v^t (cols c0..c0+255); vbin^t ----
    if (tid < 256) {
      const float* bp = pv + (size_t)par * 16 * NN + c0 + tid;
      float s = 0.f;
#pragma unroll
      for (int k = 0; k < 16; ++k) s += bp[(size_t)k * NN];
      const float* sp = SuArr + par * 256 + cb * 16;
      float sut = 0.f;
#pragma unroll
      for (int k = 0; k < 16; ++k) sut += sp[k];
      vbin = MU_B / (b * (sut + ubin));  // global Su^t + ubin^t
      const float vj = MU_C / (s + b * ubin);
      v_sh[tid] = vj;
      float sred = vj;
#pragma unroll
      for (int off = 1; off < 64; off <<= 1) sred += __shfl_xor(sred, off);
      if ((tid & 63) == 0) red_sh[tid >> 6] = sred;
    }
    __syncthreads();
    Sv_loc = red_sh[0] + red_sh[1] + red_sh[2] + red_sh[3];
  }

  // ---- epilogue: publish u^100, v^100, bin scalars ----
  __syncthreads();
  if (cb == 0 && tid < 256) u_out[r0 + tid] = u_sh[tid];
  if (rb == 0 && tid < 256) v_out[c0 + tid] = v_sh[tid];
  if (bid == 0 && tid == 0) { u_out[NN] = ubin; v_out[NN] = vbin; }
}

// ------- epilogue: out = exp(c)*u*v*8192*KSCALE, fused row max/argmax -----
__global__ __launch_bounds__(256) void final_kernel(
    const float* __restrict__ C, const float* __restrict__ u,
    const float* __restrict__ v, const float* __restrict__ alpha_p,
    float* __restrict__ out, float* __restrict__ rowmax,
    int* __restrict__ rowidx) {
  const int wave = threadIdx.x >> 6, lane = threadIdx.x & 63;
  const int row = blockIdx.x * 4 + wave;
  const float ea = expf(alpha_p[0]);
  if (row < NN) {
    const float ui = u[row] * OUT_SCALE;
    float m = -INFINITY;
    int mi = 0;
    const float* Crow = C + (long)row * NN;
    float* orow = out + (long)row * NP1;
    for (int it = 0; it < 64; ++it) {
      const int j = it * 64 + lane;
      float val = expf(Crow[j]) * ui * v[j];
      orow[j] = val;
      if (val > m) { m = val; mi = j; }
    }
#pragma unroll
    for (int off = 1; off < 64; off <<= 1) {
      float om = __shfl_xor(m, off);
      int oi = __shfl_xor(mi, off);
      if (om > m || (om == m && oi < mi)) { m = om; mi = oi; }
    }
    if (lane == 0) {
      orow[NN] = ea * ui * v[NN];
      rowmax[row] = m;
      rowidx[row] = mi;
    }
  } else if (row == NN) {
    const float ub = u[NN] * OUT_SCALE;
    float* orow = out + (long)NN * NP1;
    for (int j = lane; j < NN; j += 64) orow[j] = ea * ub * v[j];
    if (lane == 0) orow[NN] = ea * ub * v[NN];
  }
}

// ---------------- column max/argmax: 2-stage ------------------------------
__global__ __launch_bounds__(256) void colmax_part_kernel(
    const float* __restrict__ out, float* __restrict__ pmax,
    int* __restrict__ pidx) {
  const int col = blockIdx.x * 256 + threadIdx.x;
  const int rg = blockIdx.y;
  float m = -INFINITY;
  int mi = 0;
  const int r0 = rg * 256;
  for (int r = r0; r < r0 + 256; ++r) {
    float val = out[(long)r * NP1 + col];
    if (val > m) { m = val; mi = r; }
  }
  pmax[rg * NN + col] = m;
  pidx[rg * NN + col] = mi;
}

__global__ __launch_bounds__(256) void colmax_red_kernel(
    const float* __restrict__ pmax, const int* __restrict__ pidx,
    float* __restrict__ colmax, int* __restrict__ colidx) {
  const int col = blockIdx.x * 256 + threadIdx.x;
  float m = -INFINITY;
  int mi = 0;
  for (int rg = 0; rg < 16; ++rg) {
    float val = pmax[rg * NN + col];
    if (val > m) { m = val; mi = pidx[rg * NN + col]; }
  }
  colmax[col] = m;
  colidx[col] = mi;
}

// ---------------- mutual matching -----------------------------------------
__global__ void match0_kernel(const float* __restrict__ rowmax,
                              const int* __restrict__ rowidx,
                              const int* __restrict__ colidx,
                              float* __restrict__ out_idx0,
                              float* __restrict__ out_msc0,
                              int* __restrict__ valid0) {
  const int i = blockIdx.x * 256 + threadIdx.x;
  if (i >= NN) return;
  const int i0 = rowidx[i];
  const bool mutual = (colidx[i0] == i);
  const float ms = mutual ? rowmax[i] : 0.f;
  const bool v0 = mutual && (ms > 0.2f);
  out_msc0[i] = ms;
  out_idx0[i] = v0 ? (float)i0 : -1.f;
  valid0[i] = v0 ? 1 : 0;
}

__global__ void match1_kernel(const int* __restrict__ rowidx,
                              const int* __restrict__ colidx,
                              const float* __restrict__ msc0,
                              const int* __restrict__ valid0,
                              float* __restrict__ out_idx1,
                              float* __restrict__ out_msc1) {
  const int j = blockIdx.x * 256 + threadIdx.x;
  if (j >= NN) return;
  const int i1 = colidx[j];
  const bool mutual = (rowidx[i1] == j);
  const float ms = mutual ? msc0[i1] : 0.f;
  const bool v1 = mutual && (valid0[i1] != 0);
  out_msc1[j] = ms;
  out_idx1[j] = v1 ? (float)i1 : -1.f;
}

// ---------------- launch ---------------------------------------------------
extern "C" void kernel_launch(void* const* d_in, const int* in_sizes, int n_in,
                              void* d_out, int out_size, void* d_ws,
                              size_t ws_size, hipStream_t stream) {
  const float* mdesc0 = (const float*)d_in[0];  // (128, 4096)
  const float* mdesc1 = (const float*)d_in[1];  // (128, 4096)
  const float* alpha = (const float*)d_in[2];   // scalar

  char* ws = (char*)d_ws;
  size_t off = 0;
  float* c = (float*)(ws + off); off += (size_t)NN * NN * 4;  // 64 MiB
  float* pu = (float*)(ws + off); off += 2 * 16 * NN * 4;     // 512 KiB
  float* pv = (float*)(ws + off); off += 2 * 16 * NN * 4;     // 512 KiB
  float* SvArr = (float*)(ws + off); off += 2 * 256 * 4;
  float* SuArr = (float*)(ws + off); off += 2 * 256 * 4;
  int* rowflag = (int*)(ws + off); off += 16 * 16 * FLAG_STRIDE * 4;
  int* colflag = (int*)(ws + off); off += 16 * 16 * FLAG_STRIDE * 4;
  float* u = (float*)(ws + off); off += 16640;
  float* v = (float*)(ws + off); off += 16640;
  float* rowmax = (float*)(ws + off); off += 16384;
  int* rowidx = (int*)(ws + off); off += 16384;
  float* pmax = (float*)(ws + off); off += 16 * NN * 4;
  int* pidx = (int*)(ws + off); off += 16 * NN * 4;
  float* colmax = (float*)(ws + off); off += 16384;
  int* colidx = (int*)(ws + off); off += 16384;
  int* valid0 = (int*)(ws + off); off += 16384;

  float* out = (float*)d_out;
  float* out_idx0 = out + (size_t)NP1 * NP1;
  float* out_idx1 = out_idx0 + NN;
  float* out_msc0 = out_idx1 + NN;
  float* out_msc1 = out_msc0 + NN;

  hipFuncSetAttribute((const void*)sinkhorn_persistent,
                      hipFuncAttributeMaxDynamicSharedMemorySize, SMEM_BYTES);

  gemm_kernel<<<dim3(64, 64), 256, 0, stream>>>(mdesc0, mdesc1, c);
  sinkhorn_persistent<<<NBLK, TPB, SMEM_BYTES, stream>>>(
      c, alpha, pu, pv, SvArr, SuArr, rowflag, colflag, u, v);
  final_kernel<<<1025, 256, 0, stream>>>(c, u, v, alpha, out, rowmax, rowidx);
  colmax_part_kernel<<<dim3(16, 16), 256, 0, stream>>>(out, pmax, pidx);
  colmax_red_kernel<<<16, 256, 0, stream>>>(pmax, pidx, colmax, colidx);
  match0_kernel<<<16, 256, 0, stream>>>(rowmax, rowidx, colidx, out_idx0,
                                        out_msc0, valid0);
  match1_kernel<<<16, 256, 0, stream>>>(rowidx, colidx, out_msc0, valid0,
                                        out_idx1, out_msc1);
}

// Round 4
// 934.587 us; speedup vs baseline: 7.5448x; 7.5448x over previous
//
#include <hip/hip_runtime.h>
#include <hip/hip_fp16.h>
#include <math.h>

// Problem constants
#define NN 4096
#define NP1 4097
#define DD 128
#define ITERS 100
#define NBLK 256      // persistent blocks = 16x16 tile grid, 1 per CU
#define TPB 512
#define LDA 264       // LDS tile row stride in halfs (256 + 8 pad)
#define FLAG_STRIDE 16  // dwords per flag slot (64B line each)

#define KSCALE 0.0625f
#define MU_C (1.0f/8192.0f)   // exp(norm)
#define MU_B 0.5f             // ns/(ms+ns)
#define INV_SQRT_D 0.08838834764831845f
#define OUT_SCALE 512.0f      // 8192 * KSCALE

#define SMEM_BYTES (135168 + (256 + 256 + 2048 + 16 + 8) * 4)

// System-scope relaxed accesses: sc0+sc1 -> write-through / cache-bypass to
// the coherence point (Infinity Cache). Cross-XCD coherent with NO fences,
// NO buffer_wbl2/buffer_inv tag walks (the R2/R3 killer).
__device__ __forceinline__ float sysld(const float* p) {
  return __hip_atomic_load(p, __ATOMIC_RELAXED, __HIP_MEMORY_SCOPE_SYSTEM);
}
__device__ __forceinline__ void syst(float* p, float v) {
  __hip_atomic_store(p, v, __ATOMIC_RELAXED, __HIP_MEMORY_SCOPE_SYSTEM);
}

// 16-block group barrier, fence-free. 0xAA-poisoned flags read negative, so
// gen >= 1 needs no init. __syncthreads + s_waitcnt(0) drains store acks
// (write-through completes at coherence point) before the flag store.
__device__ __forceinline__ void group_bar(int* flags, int self, int gen) {
  __syncthreads();
  __builtin_amdgcn_s_waitcnt(0);
  if (threadIdx.x == 0)
    __hip_atomic_store(flags + self * FLAG_STRIDE, gen, __ATOMIC_RELAXED,
                       __HIP_MEMORY_SCOPE_SYSTEM);
  if (threadIdx.x < 16) {
    while (__hip_atomic_load(flags + threadIdx.x * FLAG_STRIDE, __ATOMIC_RELAXED,
                             __HIP_MEMORY_SCOPE_SYSTEM) < gen)
      __builtin_amdgcn_s_sleep(1);
  }
  __syncthreads();
}

// ---------------- GEMM: c[i][j] = sum_d A[d][i]*B[d][j] / sqrt(128) -------
__global__ __launch_bounds__(256) void gemm_kernel(
    const float* __restrict__ A, const float* __restrict__ B,
    float* __restrict__ C) {
  __shared__ float As[16][64];
  __shared__ float Bs[16][64];
  const int tid = threadIdx.x;
  const int tx = tid & 15, ty = tid >> 4;
  const int i0 = blockIdx.y * 64, j0 = blockIdx.x * 64;
  float acc[4][4] = {};
  for (int k0 = 0; k0 < DD; k0 += 16) {
#pragma unroll
    for (int l = 0; l < 4; ++l) {
      int idx = tid + l * 256;
      int r = idx >> 6, cc = idx & 63;
      As[r][cc] = A[(k0 + r) * NN + i0 + cc];
      Bs[r][cc] = B[(k0 + r) * NN + j0 + cc];
    }
    __syncthreads();
#pragma unroll
    for (int kk = 0; kk < 16; ++kk) {
      float a[4], b[4];
#pragma unroll
      for (int r = 0; r < 4; ++r) a[r] = As[kk][ty * 4 + r];
#pragma unroll
      for (int s = 0; s < 4; ++s) b[s] = Bs[kk][tx * 4 + s];
#pragma unroll
      for (int r = 0; r < 4; ++r)
#pragma unroll
        for (int s = 0; s < 4; ++s) acc[r][s] += a[r] * b[s];
    }
    __syncthreads();
  }
  for (int r = 0; r < 4; ++r)
    for (int s = 0; s < 4; ++s)
      C[(long)(i0 + ty * 4 + r) * NN + j0 + tx * 4 + s] = acc[r][s] * INV_SQRT_D;
}

// -------- persistent Sinkhorn: 100 iterations, K tiles resident in LDS ----
// Block (rb,cb) owns tile rows [rb*256,..), cols [cb*256,..).
// Phase A syncs row group rb; phase B syncs column group cb. Transitivity of
// alternating group syncs propagates the bin scalars globally. All
// cross-block data moves via system-scope relaxed atomics (fence-free).
__global__ __launch_bounds__(TPB, 1) void sinkhorn_persistent(
    const float* __restrict__ C, const float* __restrict__ alpha_p,
    float* __restrict__ pu, float* __restrict__ pv,
    float* __restrict__ SvArr, float* __restrict__ SuArr,
    int* __restrict__ rowflag, int* __restrict__ colflag,
    float* __restrict__ u_out, float* __restrict__ v_out) {
  extern __shared__ char smem[];
  __half* tile = (__half*)smem;                  // 256 x 264 halfs
  float* v_sh = (float*)(smem + 135168);         // 256
  float* u_sh = v_sh + 256;                      // 256
  float* scratch = u_sh + 256;                   // 2048
  float* slot_sh = scratch + 2048;               // 16
  float* red_sh = slot_sh + 16;                  // 8

  const int tid = threadIdx.x;
  const int bid = blockIdx.x;
  const int rb = bid >> 4, cb = bid & 15;
  const int r0 = rb * 256, c0 = cb * 256;
  const float b = __expf(alpha_p[0]) * KSCALE;

  // ---- load tile: exp(c)*KSCALE -> fp16 LDS ----
  {
    const int l = tid & 63;   // cols 4l..4l+3
    const int rr = tid >> 6;  // 8 rows per sweep
    for (int base = 0; base < 256; base += 8) {
      const int row = base + rr;
      const float4 x =
          *(const float4*)(C + (size_t)(r0 + row) * NN + c0 + l * 4);
      __half2 p0, p1;
      p0.x = __float2half(__expf(x.x) * KSCALE);
      p0.y = __float2half(__expf(x.y) * KSCALE);
      p1.x = __float2half(__expf(x.z) * KSCALE);
      p1.y = __float2half(__expf(x.w) * KSCALE);
      union { __half2 h[2]; float2 f; } uu;
      uu.h[0] = p0; uu.h[1] = p1;
      *(float2*)(tile + row * LDA + l * 4) = uu.f;
    }
  }

  float ubin = 1.0f, vbin = 1.0f;  // bin recurrences (v^0 = 1, vbin^0 = 1)
  float Sv_loc = 256.0f;           // local sum of v^0 over this col group
  int gen = 0;

  for (int t = 1; t <= ITERS; ++t) {
    const int par = (t - 1) & 1;
    if (t == 1) {
      if (tid < 256) v_sh[tid] = 1.0f;
    }
    __syncthreads();  // v_sh (v^{t-1}) visible to all

    // ---- phase A: row-partials of K v^{t-1} ----
    {
      const int l = tid & 63, wv = tid >> 6;
      const int g = l >> 3, cs = l & 7;
      float vseg[32];
      {
        const float4* vp = (const float4*)(v_sh + cs * 32);
#pragma unroll
        for (int k = 0; k < 8; ++k) {
          float4 q = vp[k];
          vseg[4 * k] = q.x; vseg[4 * k + 1] = q.y;
          vseg[4 * k + 2] = q.z; vseg[4 * k + 3] = q.w;
        }
      }
      float* pu_w = pu + (size_t)(par * 16 + cb) * NN + r0;
#pragma unroll
      for (int ii = 0; ii < 4; ++ii) {
        const int row = wv * 32 + ii * 8 + g;
        const float4* kp4 = (const float4*)(tile + row * LDA + cs * 32);
        float acc = 0.f;
#pragma unroll
        for (int q = 0; q < 4; ++q) {
          float4 kraw = kp4[q];
          const __half2* h = (const __half2*)&kraw;
#pragma unroll
          for (int m = 0; m < 4; ++m) {
            float2 kf = __half22float2(h[m]);
            acc += kf.x * vseg[q * 8 + 2 * m] + kf.y * vseg[q * 8 + 2 * m + 1];
          }
        }
        acc += __shfl_xor(acc, 1);
        acc += __shfl_xor(acc, 2);
        acc += __shfl_xor(acc, 4);
        if (cs == 0) syst(&pu_w[row], acc);
      }
    }
    if (tid == 0) syst(&SvArr[(par * 16 + rb) * 16 + cb], Sv_loc);
    ++gen;
    group_bar(rowflag + rb * 16 * FLAG_STRIDE, cb, gen);

    // ---- assemble u^t (rows r0..r0+255); ubin^t ----
    if (tid < 16) slot_sh[tid] = sysld(&SvArr[par * 256 + rb * 16 + tid]);
    float rsum = 0.f;
    if (tid < 256) {
      const float* bp = pu + (size_t)par * 16 * NN + r0 + tid;
#pragma unroll
      for (int k = 0; k < 16; ++k) rsum += sysld(&bp[(size_t)k * NN]);
    }
    __syncthreads();
    if (tid < 256) {
      float svt = 0.f;
#pragma unroll
      for (int k = 0; k < 16; ++k) svt += slot_sh[k];
      ubin = MU_B / (b * (svt + vbin));  // global Sv^{t-1} + vbin^{t-1}
      const float ui = MU_C / (rsum + b * vbin);
      u_sh[tid] = ui;
      float sred = ui;
#pragma unroll
      for (int off = 1; off < 64; off <<= 1) sred += __shfl_xor(sred, off);
      if ((tid & 63) == 0) red_sh[tid >> 6] = sred;
    }
    __syncthreads();
    const float Su_loc = red_sh[0] + red_sh[1] + red_sh[2] + red_sh[3];

    // ---- phase B: col-partials of K^T u^t ----
    {
      const int l = tid & 63, wv = tid >> 6;
      float fa0 = 0.f, fa1 = 0.f, fa2 = 0.f, fa3 = 0.f;
#pragma unroll 8
      for (int r = 0; r < 32; ++r) {
        const int row = wv * 32 + r;
        const float ur = u_sh[row];
        float2 kraw = *(const float2*)(tile + row * LDA + l * 4);
        const __half2* h = (const __half2*)&kraw;
        float2 k0 = __half22float2(h[0]), k1 = __half22float2(h[1]);
        fa0 += k0.x * ur; fa1 += k0.y * ur;
        fa2 += k1.x * ur; fa3 += k1.y * ur;
      }
      float4 fv; fv.x = fa0; fv.y = fa1; fv.z = fa2; fv.w = fa3;
      *(float4*)(scratch + (wv * 64 + l) * 4) = fv;
    }
    __syncthreads();
    if (tid < 256) {
      float s = 0.f;
#pragma unroll
      for (int k = 0; k < 8; ++k) s += scratch[k * 256 + tid];
      syst(&pv[(size_t)(par * 16 + rb) * NN + c0 + tid], s);
    }
    if (tid == 0) syst(&SuArr[(par * 16 + cb) * 16 + rb], Su_loc);
    ++gen;
    group_bar(colflag + cb * 16 * FLAG_STRIDE, rb, gen);

    // ---- assemble v^t (cols c0..c0+255); vbin^t ----
    if (tid < 16) slot_sh[tid] = sysld(&SuArr[par * 256 + cb * 16 + tid]);
    float csum = 0.f;
    if (tid < 256) {
      const float* bp = pv + (size_t)par * 16 * NN + c0 + tid;
#pragma unroll
      for (int k = 0; k < 16; ++k) csum += sysld(&bp[(size_t)k * NN]);
    }
    __syncthreads();
    if (tid < 256) {
      float sut = 0.f;
#pragma unroll
      for (int k = 0; k < 16; ++k) sut += slot_sh[k];
      vbin = MU_B / (b * (sut + ubin));  // global Su^t + ubin^t
      const float vj = MU_C / (csum + b * ubin);
      v_sh[tid] = vj;
      float sred = vj;
#pragma unroll
      for (int off = 1; off < 64; off <<= 1) sred += __shfl_xor(sred, off);
      if ((tid & 63) == 0) red_sh[tid >> 6] = sred;
    }
    __syncthreads();
    Sv_loc = red_sh[0] + red_sh[1] + red_sh[2] + red_sh[3];
  }

  // ---- epilogue: publish u^100, v^100, bin scalars ----
  __syncthreads();
  if (cb == 0 && tid < 256) u_out[r0 + tid] = u_sh[tid];
  if (rb == 0 && tid < 256) v_out[c0 + tid] = v_sh[tid];
  if (bid == 0 && tid == 0) { u_out[NN] = ubin; v_out[NN] = vbin; }
}

// ------- epilogue: out = exp(c)*u*v*8192*KSCALE, fused row max/argmax -----
__global__ __launch_bounds__(256) void final_kernel(
    const float* __restrict__ C, const float* __restrict__ u,
    const float* __restrict__ v, const float* __restrict__ alpha_p,
    float* __restrict__ out, float* __restrict__ rowmax,
    int* __restrict__ rowidx) {
  const int wave = threadIdx.x >> 6, lane = threadIdx.x & 63;
  const int row = blockIdx.x * 4 + wave;
  const float ea = expf(alpha_p[0]);
  if (row < NN) {
    const float ui = u[row] * OUT_SCALE;
    float m = -INFINITY;
    int mi = 0;
    const float* Crow = C + (long)row * NN;
    float* orow = out + (long)row * NP1;
    for (int it = 0; it < 64; ++it) {
      const int j = it * 64 + lane;
      float val = expf(Crow[j]) * ui * v[j];
      orow[j] = val;
      if (val > m) { m = val; mi = j; }
    }
#pragma unroll
    for (int off = 1; off < 64; off <<= 1) {
      float om = __shfl_xor(m, off);
      int oi = __shfl_xor(mi, off);
      if (om > m || (om == m && oi < mi)) { m = om; mi = oi; }
    }
    if (lane == 0) {
      orow[NN] = ea * ui * v[NN];
      rowmax[row] = m;
      rowidx[row] = mi;
    }
  } else if (row == NN) {
    const float ub = u[NN] * OUT_SCALE;
    float* orow = out + (long)NN * NP1;
    for (int j = lane; j < NN; j += 64) orow[j] = ea * ub * v[j];
    if (lane == 0) orow[NN] = ea * ub * v[NN];
  }
}

// ---------------- column max/argmax: 2-stage ------------------------------
__global__ __launch_bounds__(256) void colmax_part_kernel(
    const float* __restrict__ out, float* __restrict__ pmax,
    int* __restrict__ pidx) {
  const int col = blockIdx.x * 256 + threadIdx.x;
  const int rg = blockIdx.y;
  float m = -INFINITY;
  int mi = 0;
  const int r0 = rg * 256;
  for (int r = r0; r < r0 + 256; ++r) {
    float val = out[(long)r * NP1 + col];
    if (val > m) { m = val; mi = r; }
  }
  pmax[rg * NN + col] = m;
  pidx[rg * NN + col] = mi;
}

__global__ __launch_bounds__(256) void colmax_red_kernel(
    const float* __restrict__ pmax, const int* __restrict__ pidx,
    float* __restrict__ colmax, int* __restrict__ colidx) {
  const int col = blockIdx.x * 256 + threadIdx.x;
  float m = -INFINITY;
  int mi = 0;
  for (int rg = 0; rg < 16; ++rg) {
    float val = pmax[rg * NN + col];
    if (val > m) { m = val; mi = pidx[rg * NN + col]; }
  }
  colmax[col] = m;
  colidx[col] = mi;
}

// ---------------- mutual matching -----------------------------------------
__global__ void match0_kernel(const float* __restrict__ rowmax,
                              const int* __restrict__ rowidx,
                              const int* __restrict__ colidx,
                              float* __restrict__ out_idx0,
                              float* __restrict__ out_msc0,
                              int* __restrict__ valid0) {
  const int i = blockIdx.x * 256 + threadIdx.x;
  if (i >= NN) return;
  const int i0 = rowidx[i];
  const bool mutual = (colidx[i0] == i);
  const float ms = mutual ? rowmax[i] : 0.f;
  const bool v0 = mutual && (ms > 0.2f);
  out_msc0[i] = ms;
  out_idx0[i] = v0 ? (float)i0 : -1.f;
  valid0[i] = v0 ? 1 : 0;
}

__global__ void match1_kernel(const int* __restrict__ rowidx,
                              const int* __restrict__ colidx,
                              const float* __restrict__ msc0,
                              const int* __restrict__ valid0,
                              float* __restrict__ out_idx1,
                              float* __restrict__ out_msc1) {
  const int j = blockIdx.x * 256 + threadIdx.x;
  if (j >= NN) return;
  const int i1 = colidx[j];
  const bool mutual = (rowidx[i1] == j);
  const float ms = mutual ? msc0[i1] : 0.f;
  const bool v1 = mutual && (valid0[i1] != 0);
  out_msc1[j] = ms;
  out_idx1[j] = v1 ? (float)i1 : -1.f;
}

// ---------------- launch ---------------------------------------------------
extern "C" void kernel_launch(void* const* d_in, const int* in_sizes, int n_in,
                              void* d_out, int out_size, void* d_ws,
                              size_t ws_size, hipStream_t stream) {
  const float* mdesc0 = (const float*)d_in[0];  // (128, 4096)
  const float* mdesc1 = (const float*)d_in[1];  // (128, 4096)
  const float* alpha = (const float*)d_in[2];   // scalar

  char* ws = (char*)d_ws;
  size_t off = 0;
  float* c = (float*)(ws + off); off += (size_t)NN * NN * 4;  // 64 MiB
  float* pu = (float*)(ws + off); off += 2 * 16 * NN * 4;     // 512 KiB
  float* pv = (float*)(ws + off); off += 2 * 16 * NN * 4;     // 512 KiB
  float* SvArr = (float*)(ws + off); off += 2 * 256 * 4;
  float* SuArr = (float*)(ws + off); off += 2 * 256 * 4;
  int* rowflag = (int*)(ws + off); off += 16 * 16 * FLAG_STRIDE * 4;
  int* colflag = (int*)(ws + off); off += 16 * 16 * FLAG_STRIDE * 4;
  float* u = (float*)(ws + off); off += 16640;
  float* v = (float*)(ws + off); off += 16640;
  float* rowmax = (float*)(ws + off); off += 16384;
  int* rowidx = (int*)(ws + off); off += 16384;
  float* pmax = (float*)(ws + off); off += 16 * NN * 4;
  int* pidx = (int*)(ws + off); off += 16 * NN * 4;
  float* colmax = (float*)(ws + off); off += 16384;
  int* colidx = (int*)(ws + off); off += 16384;
  int* valid0 = (int*)(ws + off); off += 16384;

  float* out = (float*)d_out;
  float* out_idx0 = out + (size_t)NP1 * NP1;
  float* out_idx1 = out_idx0 + NN;
  float* out_msc0 = out_idx1 + NN;
  float* out_msc1 = out_msc0 + NN;

  hipFuncSetAttribute((const void*)sinkhorn_persistent,
                      hipFuncAttributeMaxDynamicSharedMemorySize, SMEM_BYTES);

  gemm_kernel<<<dim3(64, 64), 256, 0, stream>>>(mdesc0, mdesc1, c);
  sinkhorn_persistent<<<NBLK, TPB, SMEM_BYTES, stream>>>(
      c, alpha, pu, pv, SvArr, SuArr, rowflag, colflag, u, v);
  final_kernel<<<1025, 256, 0, stream>>>(c, u, v, alpha, out, rowmax, rowidx);
  colmax_part_kernel<<<dim3(16, 16), 256, 0, stream>>>(out, pmax, pidx);
  colmax_red_kernel<<<16, 256, 0, stream>>>(pmax, pidx, colmax, colidx);
  match0_kernel<<<16, 256, 0, stream>>>(rowmax, rowidx, colidx, out_idx0,
                                        out_msc0, valid0);
  match1_kernel<<<16, 256, 0, stream>>>(rowidx, colidx, out_msc0, valid0,
                                        out_idx1, out_msc1);
}